// Round 1
// baseline (457.928 us; speedup 1.0000x reference)
//
#include <hip/hip_runtime.h>
#include <math.h>

#define N_NODES 100000
#define N_EDGES 1000000
#define IN_F 128
#define H_F 64
#define THRV 0.1f
#define LN_EPS 1e-5f
#define GRID_AGG 4096

static __device__ __forceinline__ float wave_sum(float x) {
  for (int o = 32; o > 0; o >>= 1) x += __shfl_xor(x, o, 64);
  return x;
}
static __device__ __forceinline__ float wave_max(float x) {
  for (int o = 32; o > 0; o >>= 1) x = fmaxf(x, __shfl_xor(x, o, 64));
  return x;
}

__global__ void k_count(const int* __restrict__ dst, int* __restrict__ indeg) {
  int e = blockIdx.x * blockDim.x + threadIdx.x;
  if (e < N_EDGES) atomicAdd(&indeg[dst[e]], 1);
}

// Block scans a 1024-chunk of indeg -> within-block exclusive prefix in offs,
// block total in partials[blockIdx].
__global__ void k_scan_a(const int* __restrict__ indeg, int* __restrict__ offs,
                         int* __restrict__ partials) {
  __shared__ int lds[256];
  int base = blockIdx.x * 1024;
  int t = threadIdx.x;
  int v[4];
  int s = 0;
#pragma unroll
  for (int i = 0; i < 4; ++i) {
    int idx = base + t * 4 + i;
    v[i] = (idx < N_NODES) ? indeg[idx] : 0;
    s += v[i];
  }
  lds[t] = s;
  __syncthreads();
  int val = s;
  for (int o = 1; o < 256; o <<= 1) {
    int y = (t >= o) ? lds[t - o] : 0;
    __syncthreads();
    val += y;
    lds[t] = val;
    __syncthreads();
  }
  int excl = val - s;
#pragma unroll
  for (int i = 0; i < 4; ++i) {
    int idx = base + t * 4 + i;
    if (idx < N_NODES) offs[idx] = excl;
    excl += v[i];
  }
  if (t == 255) partials[blockIdx.x] = val;
}

__global__ void k_scan_b(int* __restrict__ partials, int nblk) {
  __shared__ int lds[128];
  int t = threadIdx.x;  // 128 threads
  int v = (t < nblk) ? partials[t] : 0;
  lds[t] = v;
  __syncthreads();
  int val = v;
  for (int o = 1; o < 128; o <<= 1) {
    int y = (t >= o) ? lds[t - o] : 0;
    __syncthreads();
    val += y;
    lds[t] = val;
    __syncthreads();
  }
  if (t < nblk) partials[t] = val - v;  // exclusive
}

__global__ void k_scan_c(int* __restrict__ offs, const int* __restrict__ partials,
                         int* __restrict__ cursor) {
  int i = blockIdx.x * blockDim.x + threadIdx.x;
  if (i < N_NODES) {
    int o = offs[i] + partials[i >> 10];
    offs[i] = o;
    cursor[i] = o;
  }
}

__global__ void k_scatter(const int* __restrict__ src, const int* __restrict__ dst,
                          int* __restrict__ cursor, int* __restrict__ csr_src) {
  int e = blockIdx.x * blockDim.x + threadIdx.x;
  if (e < N_EDGES) {
    int d = dst[e];
    int pos = atomicAdd(&cursor[d], 1);
    csr_src[pos] = src[e];
  }
}

// Y[nrows][64] = X[nrows][K] @ W[K][64]. One wave computes 8 rows; lane = col.
// W^T staged in LDS with padded leading dim (conflict-free ds_read_b128).
// Row base forced to SGPR so x-row loads become scalar loads.
template <int K>
__global__ __launch_bounds__(256) void k_gemm(const float* __restrict__ X,
                                              const float* __restrict__ W,
                                              float* __restrict__ Y, int nrows) {
  constexpr int KP = K + 4;
  __shared__ float wt[64][KP];
  int t = threadIdx.x;
  for (int idx = t; idx < K * 64; idx += 256) {
    int k = idx >> 6, c = idx & 63;
    wt[c][k] = W[idx];
  }
  __syncthreads();
  int lane = t & 63;
  int wid = blockIdx.x * 4 + (t >> 6);
  int nwaves = gridDim.x * 4;
  int ngroups = nrows >> 3;  // nrows % 8 == 0 (100000/8 = 12500)
  for (int g = wid; g < ngroups; g += nwaves) {
    int row0 = __builtin_amdgcn_readfirstlane(g << 3);
    const float* xp = X + (size_t)row0 * K;
    float acc[8];
#pragma unroll
    for (int r = 0; r < 8; ++r) acc[r] = 0.f;
    for (int k = 0; k < K; k += 4) {
      float4 w4 = *(const float4*)&wt[lane][k];
#pragma unroll
      for (int r = 0; r < 8; ++r) {
        float4 x4 = *(const float4*)(xp + r * K + k);
        acc[r] = fmaf(x4.x, w4.x, acc[r]);
        acc[r] = fmaf(x4.y, w4.y, acc[r]);
        acc[r] = fmaf(x4.z, w4.z, acc[r]);
        acc[r] = fmaf(x4.w, w4.w, acc[r]);
      }
    }
#pragma unroll
    for (int r = 0; r < 8; ++r) Y[(row0 + r) * 64 + lane] = acc[r];
  }
}

// Layer-0 aggregation fused with +b1, LayerNorm, ReLU, score s[v], block min/max.
__global__ __launch_bounds__(256) void k_agg1(
    const float* __restrict__ h1, const int* __restrict__ offs,
    const int* __restrict__ indeg, const int* __restrict__ csr_src,
    const float* __restrict__ b1, const float* __restrict__ gamma,
    const float* __restrict__ beta, float* __restrict__ h, float* __restrict__ s,
    float* __restrict__ mmpart) {
  int lane = threadIdx.x & 63;
  int wid = blockIdx.x * 4 + (threadIdx.x >> 6);
  int nw = gridDim.x * 4;
  float bmin = __builtin_inff(), bmax = -__builtin_inff();
  for (int v = wid; v < N_NODES; v += nw) {
    int beg = offs[v];
    int deg = indeg[v];
    float disv = rsqrtf((float)deg + 1.f);
    float acc = 0.f;
    for (int j = 0; j < deg; ++j) {
      int u = csr_src[beg + j];
      float disu = rsqrtf((float)indeg[u] + 1.f);
      acc = fmaf(h1[u * 64 + lane], disu, acc);
    }
    acc = disv * fmaf(disv, h1[v * 64 + lane], acc);
    acc += b1[lane];
    float mu = wave_sum(acc) * (1.f / 64.f);
    float d = acc - mu;
    float var = wave_sum(d * d) * (1.f / 64.f);
    float hn = d * rsqrtf(var + LN_EPS) * gamma[lane] + beta[lane];
    hn = fmaxf(hn, 0.f);
    h[v * 64 + lane] = hn;
    float sv = sqrtf(wave_sum(hn * hn));  // wave-uniform
    if (lane == 0) s[v] = sv;
    bmin = fminf(bmin, sv);
    bmax = fmaxf(bmax, sv);
  }
  __shared__ float lmin[4], lmax[4];
  if ((threadIdx.x & 63) == 0) {
    lmin[threadIdx.x >> 6] = bmin;
    lmax[threadIdx.x >> 6] = bmax;
  }
  __syncthreads();
  if (threadIdx.x == 0) {
    mmpart[blockIdx.x * 2] = fminf(fminf(lmin[0], lmin[1]), fminf(lmin[2], lmin[3]));
    mmpart[blockIdx.x * 2 + 1] = fmaxf(fmaxf(lmax[0], lmax[1]), fmaxf(lmax[2], lmax[3]));
  }
}

__global__ void k_minmax2(const float* __restrict__ mmpart, float* __restrict__ smm,
                          int nblk) {
  int t = threadIdx.x;  // 256
  float mn = __builtin_inff(), mx = -__builtin_inff();
  for (int i = t; i < nblk; i += 256) {
    mn = fminf(mn, mmpart[i * 2]);
    mx = fmaxf(mx, mmpart[i * 2 + 1]);
  }
  for (int o = 32; o; o >>= 1) {
    mn = fminf(mn, __shfl_xor(mn, o, 64));
    mx = fmaxf(mx, __shfl_xor(mx, o, 64));
  }
  __shared__ float a[4], b[4];
  if ((t & 63) == 0) { a[t >> 6] = mn; b[t >> 6] = mx; }
  __syncthreads();
  if (t == 0) {
    smm[0] = fminf(fminf(a[0], a[1]), fminf(a[2], a[3]));
    smm[1] = fmaxf(fmaxf(b[0], b[1]), fmaxf(b[2], b[3]));
  }
}

__global__ void k_dis2(const float* __restrict__ s, const float* __restrict__ smm,
                       const int* __restrict__ indeg, float* __restrict__ dis2) {
  int v = blockIdx.x * blockDim.x + threadIdx.x;
  if (v < N_NODES) {
    float inv = 1.f / (smm[1] - smm[0] + 1e-8f);
    float sn = (s[v] - smm[0]) * inv;
    float d = (sn > THRV) ? (float)indeg[v] : 0.f;
    dis2[v] = rsqrtf(d + 1.f);
  }
}

// Layer-1 masked aggregation fused with +b2 and log_softmax into d_out.
__global__ __launch_bounds__(256) void k_agg2(
    const float* __restrict__ h2, const int* __restrict__ offs,
    const int* __restrict__ indeg, const int* __restrict__ csr_src,
    const float* __restrict__ s, const float* __restrict__ smm,
    const float* __restrict__ dis2, const float* __restrict__ b2,
    float* __restrict__ out) {
  int lane = threadIdx.x & 63;
  int wid = blockIdx.x * 4 + (threadIdx.x >> 6);
  int nw = gridDim.x * 4;
  float smin = smm[0];
  float inv = 1.f / (smm[1] - smm[0] + 1e-8f);
  for (int v = wid; v < N_NODES; v += nw) {
    float disv = dis2[v];
    float acc = 0.f;
    float sn = (s[v] - smin) * inv;
    if (sn > THRV) {
      int beg = offs[v];
      int deg = indeg[v];
      for (int j = 0; j < deg; ++j) {
        int u = csr_src[beg + j];
        acc = fmaf(h2[u * 64 + lane], dis2[u], acc);
      }
    }
    acc = disv * fmaf(disv, h2[v * 64 + lane], acc);
    acc += b2[lane];
    float m = wave_max(acc);
    float p = expf(acc - m);
    float sum = wave_sum(p);
    out[v * 64 + lane] = acc - m - logf(sum);
  }
}

extern "C" void kernel_launch(void* const* d_in, const int* in_sizes, int n_in,
                              void* d_out, int out_size, void* d_ws, size_t ws_size,
                              hipStream_t stream) {
  const float* x = (const float*)d_in[0];
  const float* W1 = (const float*)d_in[1];
  const float* b1 = (const float*)d_in[2];
  const float* W2 = (const float*)d_in[3];
  const float* b2 = (const float*)d_in[4];
  const float* gamma = (const float*)d_in[5];
  const float* beta = (const float*)d_in[6];
  const int* ei = (const int*)d_in[7];
  const int* src = ei;
  const int* dst = ei + N_EDGES;
  float* out = (float*)d_out;

  char* ws = (char*)d_ws;
  size_t off = 0;
  auto alloc = [&](size_t bytes) {
    void* p = ws + off;
    off += (bytes + 255) & ~(size_t)255;
    return p;
  };
  int* indeg = (int*)alloc(N_NODES * 4);
  int* offs = (int*)alloc(N_NODES * 4);
  int* cursor = (int*)alloc(N_NODES * 4);
  int* partials = (int*)alloc(256 * 4);
  int* csr_src = (int*)alloc(N_EDGES * 4);
  float* s = (float*)alloc(N_NODES * 4);
  float* dis2 = (float*)alloc(N_NODES * 4);
  float* mmpart = (float*)alloc(GRID_AGG * 2 * 4);
  float* smm = (float*)alloc(256);
  float* h1 = (float*)alloc((size_t)N_NODES * 64 * 4);
  float* h = (float*)alloc((size_t)N_NODES * 64 * 4);
  (void)ws_size;
  (void)n_in;
  (void)in_sizes;
  (void)out_size;

  hipMemsetAsync(indeg, 0, N_NODES * 4, stream);
  k_count<<<(N_EDGES + 255) / 256, 256, 0, stream>>>(dst, indeg);
  int nblk_scan = (N_NODES + 1023) / 1024;  // 98
  k_scan_a<<<nblk_scan, 256, 0, stream>>>(indeg, offs, partials);
  k_scan_b<<<1, 128, 0, stream>>>(partials, nblk_scan);
  k_scan_c<<<(N_NODES + 255) / 256, 256, 0, stream>>>(offs, partials, cursor);
  k_scatter<<<(N_EDGES + 255) / 256, 256, 0, stream>>>(src, dst, cursor, csr_src);
  k_gemm<IN_F><<<1024, 256, 0, stream>>>(x, W1, h1, N_NODES);
  k_agg1<<<GRID_AGG, 256, 0, stream>>>(h1, offs, indeg, csr_src, b1, gamma, beta,
                                       h, s, mmpart);
  k_minmax2<<<1, 256, 0, stream>>>(mmpart, smm, GRID_AGG);
  k_dis2<<<(N_NODES + 255) / 256, 256, 0, stream>>>(s, smm, indeg, dis2);
  k_gemm<H_F><<<1024, 256, 0, stream>>>(h, W2, h1 /* reuse as h2 */, N_NODES);
  k_agg2<<<GRID_AGG, 256, 0, stream>>>(h1, offs, indeg, csr_src, s, smm, dis2, b2,
                                       out);
}

// Round 2
// 329.343 us; speedup vs baseline: 1.3904x; 1.3904x over previous
//
#include <hip/hip_runtime.h>
#include <math.h>

#define N_NODES 100000
#define N_EDGES 1000000
#define IN_F 128
#define H_F 64
#define THRV 0.1f
#define LN_EPS 1e-5f
#define GRID_AGG 2048

static __device__ __forceinline__ float wave_sum(float x) {
  for (int o = 32; o > 0; o >>= 1) x += __shfl_xor(x, o, 64);
  return x;
}
static __device__ __forceinline__ float wave_max(float x) {
  for (int o = 32; o > 0; o >>= 1) x = fmaxf(x, __shfl_xor(x, o, 64));
  return x;
}

__global__ void k_count(const int* __restrict__ dst, int* __restrict__ indeg) {
  int e = blockIdx.x * blockDim.x + threadIdx.x;
  if (e < N_EDGES) atomicAdd(&indeg[dst[e]], 1);
}

// Block scans a 1024-chunk of indeg -> within-block exclusive prefix in offs,
// block total in partials[blockIdx].
__global__ void k_scan_a(const int* __restrict__ indeg, int* __restrict__ offs,
                         int* __restrict__ partials) {
  __shared__ int lds[256];
  int base = blockIdx.x * 1024;
  int t = threadIdx.x;
  int v[4];
  int s = 0;
#pragma unroll
  for (int i = 0; i < 4; ++i) {
    int idx = base + t * 4 + i;
    v[i] = (idx < N_NODES) ? indeg[idx] : 0;
    s += v[i];
  }
  lds[t] = s;
  __syncthreads();
  int val = s;
  for (int o = 1; o < 256; o <<= 1) {
    int y = (t >= o) ? lds[t - o] : 0;
    __syncthreads();
    val += y;
    lds[t] = val;
    __syncthreads();
  }
  int excl = val - s;
#pragma unroll
  for (int i = 0; i < 4; ++i) {
    int idx = base + t * 4 + i;
    if (idx < N_NODES) offs[idx] = excl;
    excl += v[i];
  }
  if (t == 255) partials[blockIdx.x] = val;
}

__global__ void k_scan_b(int* __restrict__ partials, int nblk) {
  __shared__ int lds[128];
  int t = threadIdx.x;  // 128 threads
  int v = (t < nblk) ? partials[t] : 0;
  lds[t] = v;
  __syncthreads();
  int val = v;
  for (int o = 1; o < 128; o <<= 1) {
    int y = (t >= o) ? lds[t - o] : 0;
    __syncthreads();
    val += y;
    lds[t] = val;
    __syncthreads();
  }
  if (t < nblk) partials[t] = val - v;  // exclusive
}

// Finalize offsets, init cursor, and precompute dis1[v] = rsqrt(indeg[v]+1).
__global__ void k_scan_c(int* __restrict__ offs, const int* __restrict__ partials,
                         int* __restrict__ cursor, const int* __restrict__ indeg,
                         float* __restrict__ dis1) {
  int i = blockIdx.x * blockDim.x + threadIdx.x;
  if (i < N_NODES) {
    int o = offs[i] + partials[i >> 10];
    offs[i] = o;
    cursor[i] = o;
    dis1[i] = rsqrtf((float)indeg[i] + 1.f);
  }
}

__global__ void k_scatter(const int* __restrict__ src, const int* __restrict__ dst,
                          int* __restrict__ cursor, int* __restrict__ csr_src) {
  int e = blockIdx.x * blockDim.x + threadIdx.x;
  if (e < N_EDGES) {
    int d = dst[e];
    int pos = atomicAdd(&cursor[d], 1);
    csr_src[pos] = src[e];
  }
}

// Y[r][64] = (X[r][K] @ W[K][64]) * scale[r]. One wave computes 8 rows; lane=col.
// W^T staged in LDS with padded leading dim; row base via readfirstlane so the
// X-row loads become scalar (s_load) broadcasts.
template <int K>
__global__ __launch_bounds__(256) void k_gemm(const float* __restrict__ X,
                                              const float* __restrict__ W,
                                              const float* __restrict__ scale,
                                              float* __restrict__ Y, int nrows) {
  constexpr int KP = K + 4;
  __shared__ float wt[64][KP];
  int t = threadIdx.x;
  for (int idx = t; idx < K * 64; idx += 256) {
    int k = idx >> 6, c = idx & 63;
    wt[c][k] = W[idx];
  }
  __syncthreads();
  int lane = t & 63;
  int wid = blockIdx.x * 4 + (t >> 6);
  int nwaves = gridDim.x * 4;
  int ngroups = nrows >> 3;  // nrows % 8 == 0
  for (int g = wid; g < ngroups; g += nwaves) {
    int row0 = __builtin_amdgcn_readfirstlane(g << 3);
    const float* xp = X + (size_t)row0 * K;
    float acc[8];
#pragma unroll
    for (int r = 0; r < 8; ++r) acc[r] = 0.f;
    for (int k = 0; k < K; k += 4) {
      float4 w4 = *(const float4*)&wt[lane][k];
#pragma unroll
      for (int r = 0; r < 8; ++r) {
        float4 x4 = *(const float4*)(xp + r * K + k);
        acc[r] = fmaf(x4.x, w4.x, acc[r]);
        acc[r] = fmaf(x4.y, w4.y, acc[r]);
        acc[r] = fmaf(x4.z, w4.z, acc[r]);
        acc[r] = fmaf(x4.w, w4.w, acc[r]);
      }
    }
#pragma unroll
    for (int r = 0; r < 8; ++r)
      Y[(row0 + r) * 64 + lane] = acc[r] * scale[row0 + r];
  }
}

// Layer-0 aggregation over prescaled rows h1p (= h1 * dis1), fused with +b1,
// LayerNorm, ReLU, score s[v], block min/max partials.
__global__ __launch_bounds__(256) void k_agg1(
    const float* __restrict__ h1p, const int* __restrict__ offs,
    const int* __restrict__ indeg, const int* __restrict__ csr_src,
    const float* __restrict__ dis1, const float* __restrict__ b1,
    const float* __restrict__ gamma, const float* __restrict__ beta,
    float* __restrict__ h, float* __restrict__ s, float* __restrict__ mmpart) {
  int lane = threadIdx.x & 63;
  int wid = blockIdx.x * 4 + (threadIdx.x >> 6);
  int nw = gridDim.x * 4;
  float bmin = __builtin_inff(), bmax = -__builtin_inff();
  for (int v = wid; v < N_NODES; v += nw) {
    int beg = offs[v];
    int deg = indeg[v];
    float disv = dis1[v];
    float acc = h1p[v * 64 + lane];  // self-loop term (prescaled)
    for (int c = 0; c < deg; c += 64) {
      int m = deg - c;
      if (m > 64) m = 64;
      int ul = (lane < m) ? csr_src[beg + c + lane] : 0;
      int j = 0;
      for (; j + 8 <= m; j += 8) {
        int u0 = __shfl(ul, j + 0), u1 = __shfl(ul, j + 1);
        int u2 = __shfl(ul, j + 2), u3 = __shfl(ul, j + 3);
        int u4 = __shfl(ul, j + 4), u5 = __shfl(ul, j + 5);
        int u6 = __shfl(ul, j + 6), u7 = __shfl(ul, j + 7);
        float a0 = h1p[u0 * 64 + lane], a1 = h1p[u1 * 64 + lane];
        float a2 = h1p[u2 * 64 + lane], a3 = h1p[u3 * 64 + lane];
        float a4 = h1p[u4 * 64 + lane], a5 = h1p[u5 * 64 + lane];
        float a6 = h1p[u6 * 64 + lane], a7 = h1p[u7 * 64 + lane];
        acc += ((a0 + a1) + (a2 + a3)) + ((a4 + a5) + (a6 + a7));
      }
      for (; j < m; ++j) {
        int u = __shfl(ul, j);
        acc += h1p[u * 64 + lane];
      }
    }
    acc = disv * acc + b1[lane];
    float mu = wave_sum(acc) * (1.f / 64.f);
    float d = acc - mu;
    float var = wave_sum(d * d) * (1.f / 64.f);
    float hn = d * rsqrtf(var + LN_EPS) * gamma[lane] + beta[lane];
    hn = fmaxf(hn, 0.f);
    h[v * 64 + lane] = hn;
    float sv = sqrtf(wave_sum(hn * hn));  // wave-uniform
    if (lane == 0) s[v] = sv;
    bmin = fminf(bmin, sv);
    bmax = fmaxf(bmax, sv);
  }
  __shared__ float lmin[4], lmax[4];
  if ((threadIdx.x & 63) == 0) {
    lmin[threadIdx.x >> 6] = bmin;
    lmax[threadIdx.x >> 6] = bmax;
  }
  __syncthreads();
  if (threadIdx.x == 0) {
    mmpart[blockIdx.x * 2] = fminf(fminf(lmin[0], lmin[1]), fminf(lmin[2], lmin[3]));
    mmpart[blockIdx.x * 2 + 1] = fmaxf(fmaxf(lmax[0], lmax[1]), fmaxf(lmax[2], lmax[3]));
  }
}

__global__ void k_minmax2(const float* __restrict__ mmpart, float* __restrict__ smm,
                          int nblk) {
  int t = threadIdx.x;  // 256
  float mn = __builtin_inff(), mx = -__builtin_inff();
  for (int i = t; i < nblk; i += 256) {
    mn = fminf(mn, mmpart[i * 2]);
    mx = fmaxf(mx, mmpart[i * 2 + 1]);
  }
  for (int o = 32; o; o >>= 1) {
    mn = fminf(mn, __shfl_xor(mn, o, 64));
    mx = fmaxf(mx, __shfl_xor(mx, o, 64));
  }
  __shared__ float a[4], b[4];
  if ((t & 63) == 0) { a[t >> 6] = mn; b[t >> 6] = mx; }
  __syncthreads();
  if (t == 0) {
    smm[0] = fminf(fminf(a[0], a[1]), fminf(a[2], a[3]));
    smm[1] = fmaxf(fmaxf(b[0], b[1]), fmaxf(b[2], b[3]));
  }
}

__global__ void k_dis2(const float* __restrict__ s, const float* __restrict__ smm,
                       const int* __restrict__ indeg, float* __restrict__ dis2) {
  int v = blockIdx.x * blockDim.x + threadIdx.x;
  if (v < N_NODES) {
    float inv = 1.f / (smm[1] - smm[0] + 1e-8f);
    float sn = (s[v] - smm[0]) * inv;
    float d = (sn > THRV) ? (float)indeg[v] : 0.f;
    dis2[v] = rsqrtf(d + 1.f);
  }
}

// Layer-1 masked aggregation over prescaled rows h2p (= h2 * dis2), fused with
// +b2 and log_softmax into d_out.
__global__ __launch_bounds__(256) void k_agg2(
    const float* __restrict__ h2p, const int* __restrict__ offs,
    const int* __restrict__ indeg, const int* __restrict__ csr_src,
    const float* __restrict__ s, const float* __restrict__ smm,
    const float* __restrict__ dis2, const float* __restrict__ b2,
    float* __restrict__ out) {
  int lane = threadIdx.x & 63;
  int wid = blockIdx.x * 4 + (threadIdx.x >> 6);
  int nw = gridDim.x * 4;
  float smin = smm[0];
  float inv = 1.f / (smm[1] - smm[0] + 1e-8f);
  for (int v = wid; v < N_NODES; v += nw) {
    float disv = dis2[v];
    float sn = (s[v] - smin) * inv;
    float acc = h2p[v * 64 + lane];  // self-loop term (prescaled)
    if (sn > THRV) {
      int beg = offs[v];
      int deg = indeg[v];
      for (int c = 0; c < deg; c += 64) {
        int m = deg - c;
        if (m > 64) m = 64;
        int ul = (lane < m) ? csr_src[beg + c + lane] : 0;
        int j = 0;
        for (; j + 8 <= m; j += 8) {
          int u0 = __shfl(ul, j + 0), u1 = __shfl(ul, j + 1);
          int u2 = __shfl(ul, j + 2), u3 = __shfl(ul, j + 3);
          int u4 = __shfl(ul, j + 4), u5 = __shfl(ul, j + 5);
          int u6 = __shfl(ul, j + 6), u7 = __shfl(ul, j + 7);
          float a0 = h2p[u0 * 64 + lane], a1 = h2p[u1 * 64 + lane];
          float a2 = h2p[u2 * 64 + lane], a3 = h2p[u3 * 64 + lane];
          float a4 = h2p[u4 * 64 + lane], a5 = h2p[u5 * 64 + lane];
          float a6 = h2p[u6 * 64 + lane], a7 = h2p[u7 * 64 + lane];
          acc += ((a0 + a1) + (a2 + a3)) + ((a4 + a5) + (a6 + a7));
        }
        for (; j < m; ++j) {
          int u = __shfl(ul, j);
          acc += h2p[u * 64 + lane];
        }
      }
    }
    acc = disv * acc + b2[lane];
    float m = wave_max(acc);
    float p = expf(acc - m);
    float sum = wave_sum(p);
    out[v * 64 + lane] = acc - m - logf(sum);
  }
}

extern "C" void kernel_launch(void* const* d_in, const int* in_sizes, int n_in,
                              void* d_out, int out_size, void* d_ws, size_t ws_size,
                              hipStream_t stream) {
  const float* x = (const float*)d_in[0];
  const float* W1 = (const float*)d_in[1];
  const float* b1 = (const float*)d_in[2];
  const float* W2 = (const float*)d_in[3];
  const float* b2 = (const float*)d_in[4];
  const float* gamma = (const float*)d_in[5];
  const float* beta = (const float*)d_in[6];
  const int* ei = (const int*)d_in[7];
  const int* src = ei;
  const int* dst = ei + N_EDGES;
  float* out = (float*)d_out;

  char* ws = (char*)d_ws;
  size_t off = 0;
  auto alloc = [&](size_t bytes) {
    void* p = ws + off;
    off += (bytes + 255) & ~(size_t)255;
    return p;
  };
  int* indeg = (int*)alloc(N_NODES * 4);
  int* offs = (int*)alloc(N_NODES * 4);
  int* cursor = (int*)alloc(N_NODES * 4);
  int* partials = (int*)alloc(256 * 4);
  int* csr_src = (int*)alloc(N_EDGES * 4);
  float* s = (float*)alloc(N_NODES * 4);
  float* dis1 = (float*)alloc(N_NODES * 4);
  float* dis2 = (float*)alloc(N_NODES * 4);
  float* mmpart = (float*)alloc(GRID_AGG * 2 * 4);
  float* smm = (float*)alloc(256);
  float* h1 = (float*)alloc((size_t)N_NODES * 64 * 4);
  float* h = (float*)alloc((size_t)N_NODES * 64 * 4);
  (void)ws_size;
  (void)n_in;
  (void)in_sizes;
  (void)out_size;

  hipMemsetAsync(indeg, 0, N_NODES * 4, stream);
  k_count<<<(N_EDGES + 255) / 256, 256, 0, stream>>>(dst, indeg);
  int nblk_scan = (N_NODES + 1023) / 1024;  // 98
  k_scan_a<<<nblk_scan, 256, 0, stream>>>(indeg, offs, partials);
  k_scan_b<<<1, 128, 0, stream>>>(partials, nblk_scan);
  k_scan_c<<<(N_NODES + 255) / 256, 256, 0, stream>>>(offs, partials, cursor,
                                                      indeg, dis1);
  k_scatter<<<(N_EDGES + 255) / 256, 256, 0, stream>>>(src, dst, cursor, csr_src);
  k_gemm<IN_F><<<1024, 256, 0, stream>>>(x, W1, dis1, h1, N_NODES);
  k_agg1<<<GRID_AGG, 256, 0, stream>>>(h1, offs, indeg, csr_src, dis1, b1, gamma,
                                       beta, h, s, mmpart);
  k_minmax2<<<1, 256, 0, stream>>>(mmpart, smm, GRID_AGG);
  k_dis2<<<(N_NODES + 255) / 256, 256, 0, stream>>>(s, smm, indeg, dis2);
  k_gemm<H_F><<<1024, 256, 0, stream>>>(h, W2, dis2, h1 /* reuse as h2p */, N_NODES);
  k_agg2<<<GRID_AGG, 256, 0, stream>>>(h1, offs, indeg, csr_src, s, smm, dis2, b2,
                                       out);
}

// Round 3
// 313.671 us; speedup vs baseline: 1.4599x; 1.0500x over previous
//
#include <hip/hip_runtime.h>
#include <math.h>

#define N_NODES 100000
#define N_EDGES 1000000
#define IN_F 128
#define H_F 64
#define THRV 0.1f
#define LN_EPS 1e-5f
#define GRID_AGG 2048

static __device__ __forceinline__ float wave_sum(float x) {
  for (int o = 32; o > 0; o >>= 1) x += __shfl_xor(x, o, 64);
  return x;
}
static __device__ __forceinline__ float wave_max(float x) {
  for (int o = 32; o > 0; o >>= 1) x = fmaxf(x, __shfl_xor(x, o, 64));
  return x;
}

__global__ void k_count(const int* __restrict__ dst, int* __restrict__ indeg) {
  int e = blockIdx.x * blockDim.x + threadIdx.x;
  if (e < N_EDGES) atomicAdd(&indeg[dst[e]], 1);
}

// Block scans a 1024-chunk of indeg -> within-block exclusive prefix in offs,
// block total in partials[blockIdx].
__global__ void k_scan_a(const int* __restrict__ indeg, int* __restrict__ offs,
                         int* __restrict__ partials) {
  __shared__ int lds[256];
  int base = blockIdx.x * 1024;
  int t = threadIdx.x;
  int v[4];
  int s = 0;
#pragma unroll
  for (int i = 0; i < 4; ++i) {
    int idx = base + t * 4 + i;
    v[i] = (idx < N_NODES) ? indeg[idx] : 0;
    s += v[i];
  }
  lds[t] = s;
  __syncthreads();
  int val = s;
  for (int o = 1; o < 256; o <<= 1) {
    int y = (t >= o) ? lds[t - o] : 0;
    __syncthreads();
    val += y;
    lds[t] = val;
    __syncthreads();
  }
  int excl = val - s;
#pragma unroll
  for (int i = 0; i < 4; ++i) {
    int idx = base + t * 4 + i;
    if (idx < N_NODES) offs[idx] = excl;
    excl += v[i];
  }
  if (t == 255) partials[blockIdx.x] = val;
}

__global__ void k_scan_b(int* __restrict__ partials, int nblk) {
  __shared__ int lds[128];
  int t = threadIdx.x;  // 128 threads
  int v = (t < nblk) ? partials[t] : 0;
  lds[t] = v;
  __syncthreads();
  int val = v;
  for (int o = 1; o < 128; o <<= 1) {
    int y = (t >= o) ? lds[t - o] : 0;
    __syncthreads();
    val += y;
    lds[t] = val;
    __syncthreads();
  }
  if (t < nblk) partials[t] = val - v;  // exclusive
}

// Finalize offsets, init cursor, and precompute dis1[v] = rsqrt(indeg[v]+1).
__global__ void k_scan_c(int* __restrict__ offs, const int* __restrict__ partials,
                         int* __restrict__ cursor, const int* __restrict__ indeg,
                         float* __restrict__ dis1) {
  int i = blockIdx.x * blockDim.x + threadIdx.x;
  if (i < N_NODES) {
    int o = offs[i] + partials[i >> 10];
    offs[i] = o;
    cursor[i] = o;
    dis1[i] = rsqrtf((float)indeg[i] + 1.f);
  }
}

__global__ void k_scatter(const int* __restrict__ src, const int* __restrict__ dst,
                          int* __restrict__ cursor, int* __restrict__ csr_src) {
  int e = blockIdx.x * blockDim.x + threadIdx.x;
  if (e < N_EDGES) {
    int d = dst[e];
    int pos = atomicAdd(&cursor[d], 1);
    csr_src[pos] = src[e];
  }
}

// Tiled fp32 GEMM: Y[r][64] = (X[r][K] @ W[K][64]) * scale[r].
// Block = 256 threads computes a 64x64 tile. X tile staged in LDS with
// 16B-chunk XOR swizzle (conflict-free 4-row ds_read_b128); W staged linear.
// Each thread register-blocks 4 rows x 4 cols.
template <int K>
__global__ __launch_bounds__(256) void k_gemm(const float* __restrict__ X,
                                              const float* __restrict__ W,
                                              const float* __restrict__ scale,
                                              float* __restrict__ Y, int nrows) {
  constexpr int C4 = K / 4;  // 16B chunks per row
  __shared__ __align__(16) float Xs[64][K];
  __shared__ __align__(16) float Ws[K][64];
  int t = threadIdx.x;
  int rbase = blockIdx.x * 64;
  // stage X: 64 rows x C4 chunks, coalesced global, swizzled LDS chunk index
  for (int idx = t; idx < 64 * C4; idx += 256) {
    int row = idx / C4;
    int c4 = idx % C4;
    int gr = rbase + row;
    if (gr >= nrows) gr = nrows - 1;
    float4 v = *(const float4*)(X + (size_t)gr * K + c4 * 4);
    int c4s = c4 ^ (row & 7);  // C4 is 16 or 32 -> XOR stays in range
    *(float4*)&Xs[row][c4s * 4] = v;
  }
  // stage W: straight linear copy
  for (int idx = t; idx < K * 16; idx += 256) {
    ((float4*)&Ws[0][0])[idx] = ((const float4*)W)[idx];
  }
  __syncthreads();

  int tx = t & 15, ty = t >> 4;
  int r0 = ty * 4, c0 = tx * 4;
  float acc[4][4] = {};
#pragma unroll 8
  for (int k = 0; k < K; k += 4) {
    float xv[4][4], wv[4][4];
#pragma unroll
    for (int i = 0; i < 4; ++i) {
      int r = r0 + i;
      int c4s = ((k >> 2) ^ (r & 7)) << 2;
      *(float4*)xv[i] = *(const float4*)&Xs[r][c4s];
    }
#pragma unroll
    for (int j = 0; j < 4; ++j)
      *(float4*)wv[j] = *(const float4*)&Ws[k + j][c0];
#pragma unroll
    for (int i = 0; i < 4; ++i)
#pragma unroll
      for (int kk = 0; kk < 4; ++kk)
#pragma unroll
        for (int j = 0; j < 4; ++j)
          acc[i][j] = fmaf(xv[i][kk], wv[kk][j], acc[i][j]);
  }
#pragma unroll
  for (int i = 0; i < 4; ++i) {
    int gr = rbase + r0 + i;
    if (gr < nrows) {
      float sc = scale[gr];
      float4 o;
      o.x = acc[i][0] * sc;
      o.y = acc[i][1] * sc;
      o.z = acc[i][2] * sc;
      o.w = acc[i][3] * sc;
      *(float4*)(Y + (size_t)gr * 64 + c0) = o;
    }
  }
}

// Layer-0 aggregation over prescaled rows h1p (= h1 * dis1), fused with +b1,
// LayerNorm, ReLU, score s[v], block min/max partials.
__global__ __launch_bounds__(256) void k_agg1(
    const float* __restrict__ h1p, const int* __restrict__ offs,
    const int* __restrict__ indeg, const int* __restrict__ csr_src,
    const float* __restrict__ dis1, const float* __restrict__ b1,
    const float* __restrict__ gamma, const float* __restrict__ beta,
    float* __restrict__ h, float* __restrict__ s, float* __restrict__ mmpart) {
  int lane = threadIdx.x & 63;
  int wid = blockIdx.x * 4 + (threadIdx.x >> 6);
  int nw = gridDim.x * 4;
  float bmin = __builtin_inff(), bmax = -__builtin_inff();
  for (int v = wid; v < N_NODES; v += nw) {
    int beg = offs[v];
    int deg = indeg[v];
    float disv = dis1[v];
    float acc = h1p[v * 64 + lane];  // self-loop term (prescaled)
    for (int c = 0; c < deg; c += 64) {
      int m = deg - c;
      if (m > 64) m = 64;
      int ul = (lane < m) ? csr_src[beg + c + lane] : 0;
      int j = 0;
      for (; j + 8 <= m; j += 8) {
        int u0 = __shfl(ul, j + 0), u1 = __shfl(ul, j + 1);
        int u2 = __shfl(ul, j + 2), u3 = __shfl(ul, j + 3);
        int u4 = __shfl(ul, j + 4), u5 = __shfl(ul, j + 5);
        int u6 = __shfl(ul, j + 6), u7 = __shfl(ul, j + 7);
        float a0 = h1p[u0 * 64 + lane], a1 = h1p[u1 * 64 + lane];
        float a2 = h1p[u2 * 64 + lane], a3 = h1p[u3 * 64 + lane];
        float a4 = h1p[u4 * 64 + lane], a5 = h1p[u5 * 64 + lane];
        float a6 = h1p[u6 * 64 + lane], a7 = h1p[u7 * 64 + lane];
        acc += ((a0 + a1) + (a2 + a3)) + ((a4 + a5) + (a6 + a7));
      }
      for (; j < m; ++j) {
        int u = __shfl(ul, j);
        acc += h1p[u * 64 + lane];
      }
    }
    acc = disv * acc + b1[lane];
    float mu = wave_sum(acc) * (1.f / 64.f);
    float d = acc - mu;
    float var = wave_sum(d * d) * (1.f / 64.f);
    float hn = d * rsqrtf(var + LN_EPS) * gamma[lane] + beta[lane];
    hn = fmaxf(hn, 0.f);
    h[v * 64 + lane] = hn;
    float sv = sqrtf(wave_sum(hn * hn));  // wave-uniform
    if (lane == 0) s[v] = sv;
    bmin = fminf(bmin, sv);
    bmax = fmaxf(bmax, sv);
  }
  __shared__ float lmin[4], lmax[4];
  if ((threadIdx.x & 63) == 0) {
    lmin[threadIdx.x >> 6] = bmin;
    lmax[threadIdx.x >> 6] = bmax;
  }
  __syncthreads();
  if (threadIdx.x == 0) {
    mmpart[blockIdx.x * 2] = fminf(fminf(lmin[0], lmin[1]), fminf(lmin[2], lmin[3]));
    mmpart[blockIdx.x * 2 + 1] = fmaxf(fmaxf(lmax[0], lmax[1]), fmaxf(lmax[2], lmax[3]));
  }
}

__global__ void k_minmax2(const float* __restrict__ mmpart, float* __restrict__ smm,
                          int nblk) {
  int t = threadIdx.x;  // 256
  float mn = __builtin_inff(), mx = -__builtin_inff();
  for (int i = t; i < nblk; i += 256) {
    mn = fminf(mn, mmpart[i * 2]);
    mx = fmaxf(mx, mmpart[i * 2 + 1]);
  }
  for (int o = 32; o; o >>= 1) {
    mn = fminf(mn, __shfl_xor(mn, o, 64));
    mx = fmaxf(mx, __shfl_xor(mx, o, 64));
  }
  __shared__ float a[4], b[4];
  if ((t & 63) == 0) { a[t >> 6] = mn; b[t >> 6] = mx; }
  __syncthreads();
  if (t == 0) {
    smm[0] = fminf(fminf(a[0], a[1]), fminf(a[2], a[3]));
    smm[1] = fmaxf(fmaxf(b[0], b[1]), fmaxf(b[2], b[3]));
  }
}

__global__ void k_dis2(const float* __restrict__ s, const float* __restrict__ smm,
                       const int* __restrict__ indeg, float* __restrict__ dis2) {
  int v = blockIdx.x * blockDim.x + threadIdx.x;
  if (v < N_NODES) {
    float inv = 1.f / (smm[1] - smm[0] + 1e-8f);
    float sn = (s[v] - smm[0]) * inv;
    float d = (sn > THRV) ? (float)indeg[v] : 0.f;
    dis2[v] = rsqrtf(d + 1.f);
  }
}

// Layer-1 masked aggregation over prescaled rows h2p (= h2 * dis2), fused with
// +b2 and log_softmax into d_out.
__global__ __launch_bounds__(256) void k_agg2(
    const float* __restrict__ h2p, const int* __restrict__ offs,
    const int* __restrict__ indeg, const int* __restrict__ csr_src,
    const float* __restrict__ s, const float* __restrict__ smm,
    const float* __restrict__ dis2, const float* __restrict__ b2,
    float* __restrict__ out) {
  int lane = threadIdx.x & 63;
  int wid = blockIdx.x * 4 + (threadIdx.x >> 6);
  int nw = gridDim.x * 4;
  float smin = smm[0];
  float inv = 1.f / (smm[1] - smm[0] + 1e-8f);
  for (int v = wid; v < N_NODES; v += nw) {
    float disv = dis2[v];
    float sn = (s[v] - smin) * inv;
    float acc = h2p[v * 64 + lane];  // self-loop term (prescaled)
    if (sn > THRV) {
      int beg = offs[v];
      int deg = indeg[v];
      for (int c = 0; c < deg; c += 64) {
        int m = deg - c;
        if (m > 64) m = 64;
        int ul = (lane < m) ? csr_src[beg + c + lane] : 0;
        int j = 0;
        for (; j + 8 <= m; j += 8) {
          int u0 = __shfl(ul, j + 0), u1 = __shfl(ul, j + 1);
          int u2 = __shfl(ul, j + 2), u3 = __shfl(ul, j + 3);
          int u4 = __shfl(ul, j + 4), u5 = __shfl(ul, j + 5);
          int u6 = __shfl(ul, j + 6), u7 = __shfl(ul, j + 7);
          float a0 = h2p[u0 * 64 + lane], a1 = h2p[u1 * 64 + lane];
          float a2 = h2p[u2 * 64 + lane], a3 = h2p[u3 * 64 + lane];
          float a4 = h2p[u4 * 64 + lane], a5 = h2p[u5 * 64 + lane];
          float a6 = h2p[u6 * 64 + lane], a7 = h2p[u7 * 64 + lane];
          acc += ((a0 + a1) + (a2 + a3)) + ((a4 + a5) + (a6 + a7));
        }
        for (; j < m; ++j) {
          int u = __shfl(ul, j);
          acc += h2p[u * 64 + lane];
        }
      }
    }
    acc = disv * acc + b2[lane];
    float m = wave_max(acc);
    float p = expf(acc - m);
    float sum = wave_sum(p);
    out[v * 64 + lane] = acc - m - logf(sum);
  }
}

extern "C" void kernel_launch(void* const* d_in, const int* in_sizes, int n_in,
                              void* d_out, int out_size, void* d_ws, size_t ws_size,
                              hipStream_t stream) {
  const float* x = (const float*)d_in[0];
  const float* W1 = (const float*)d_in[1];
  const float* b1 = (const float*)d_in[2];
  const float* W2 = (const float*)d_in[3];
  const float* b2 = (const float*)d_in[4];
  const float* gamma = (const float*)d_in[5];
  const float* beta = (const float*)d_in[6];
  const int* ei = (const int*)d_in[7];
  const int* src = ei;
  const int* dst = ei + N_EDGES;
  float* out = (float*)d_out;

  char* ws = (char*)d_ws;
  size_t off = 0;
  auto alloc = [&](size_t bytes) {
    void* p = ws + off;
    off += (bytes + 255) & ~(size_t)255;
    return p;
  };
  int* indeg = (int*)alloc(N_NODES * 4);
  int* offs = (int*)alloc(N_NODES * 4);
  int* cursor = (int*)alloc(N_NODES * 4);
  int* partials = (int*)alloc(256 * 4);
  int* csr_src = (int*)alloc(N_EDGES * 4);
  float* s = (float*)alloc(N_NODES * 4);
  float* dis1 = (float*)alloc(N_NODES * 4);
  float* dis2 = (float*)alloc(N_NODES * 4);
  float* mmpart = (float*)alloc(GRID_AGG * 2 * 4);
  float* smm = (float*)alloc(256);
  float* h1 = (float*)alloc((size_t)N_NODES * 64 * 4);
  float* h = (float*)alloc((size_t)N_NODES * 64 * 4);
  (void)ws_size;
  (void)n_in;
  (void)in_sizes;
  (void)out_size;

  hipMemsetAsync(indeg, 0, N_NODES * 4, stream);
  k_count<<<(N_EDGES + 255) / 256, 256, 0, stream>>>(dst, indeg);
  int nblk_scan = (N_NODES + 1023) / 1024;  // 98
  k_scan_a<<<nblk_scan, 256, 0, stream>>>(indeg, offs, partials);
  k_scan_b<<<1, 128, 0, stream>>>(partials, nblk_scan);
  k_scan_c<<<(N_NODES + 255) / 256, 256, 0, stream>>>(offs, partials, cursor,
                                                      indeg, dis1);
  k_scatter<<<(N_EDGES + 255) / 256, 256, 0, stream>>>(src, dst, cursor, csr_src);
  int gemm_grid = (N_NODES + 63) / 64;  // 1563
  k_gemm<IN_F><<<gemm_grid, 256, 0, stream>>>(x, W1, dis1, h1, N_NODES);
  k_agg1<<<GRID_AGG, 256, 0, stream>>>(h1, offs, indeg, csr_src, dis1, b1, gamma,
                                       beta, h, s, mmpart);
  k_minmax2<<<1, 256, 0, stream>>>(mmpart, smm, GRID_AGG);
  k_dis2<<<(N_NODES + 255) / 256, 256, 0, stream>>>(s, smm, indeg, dis2);
  k_gemm<H_F><<<gemm_grid, 256, 0, stream>>>(h, W2, dis2, h1 /* reuse as h2p */, N_NODES);
  k_agg2<<<GRID_AGG, 256, 0, stream>>>(h1, offs, indeg, csr_src, s, smm, dis2, b2,
                                       out);
}

// Round 4
// 244.148 us; speedup vs baseline: 1.8756x; 1.2848x over previous
//
#include <hip/hip_runtime.h>
#include <math.h>

#define N_NODES 100000
#define N_EDGES 1000000
#define IN_F 128
#define H_F 64
#define THRV 0.1f
#define LN_EPS 1e-5f
#define GRID_AGG 2048

#define BSHIFT 9                 // 512 nodes per bucket
#define NB 196                   // ceil(100000 / 512)
#define EPB 2048                 // edges per partition block
#define NPB ((N_EDGES + EPB - 1) / EPB)  // 489

static __device__ __forceinline__ float wave_sum(float x) {
  for (int o = 32; o > 0; o >>= 1) x += __shfl_xor(x, o, 64);
  return x;
}
static __device__ __forceinline__ float wave_max(float x) {
  for (int o = 32; o > 0; o >>= 1) x = fmaxf(x, __shfl_xor(x, o, 64));
  return x;
}

// ---- CSR build via bucket partition (no random global scatter) ----

__global__ __launch_bounds__(256) void k_bcount(const int* __restrict__ dst,
                                                int* __restrict__ bcnt) {
  __shared__ int h[NB];
  for (int i = threadIdx.x; i < NB; i += 256) h[i] = 0;
  __syncthreads();
  int base = blockIdx.x * EPB;
  for (int i = threadIdx.x; i < EPB; i += 256) {
    int e = base + i;
    if (e < N_EDGES) atomicAdd(&h[dst[e] >> BSHIFT], 1);
  }
  __syncthreads();
  for (int i = threadIdx.x; i < NB; i += 256)
    if (h[i]) atomicAdd(&bcnt[i], h[i]);
}

__global__ void k_bscan(const int* __restrict__ bcnt, int* __restrict__ bbase,
                        int* __restrict__ bcur) {
  __shared__ int lds[256];
  int t = threadIdx.x;
  int v = (t < NB) ? bcnt[t] : 0;
  lds[t] = v;
  __syncthreads();
  int val = v;
  for (int o = 1; o < 256; o <<= 1) {
    int y = (t >= o) ? lds[t - o] : 0;
    __syncthreads();
    val += y;
    lds[t] = val;
    __syncthreads();
  }
  if (t < NB) {
    int ex = val - v;
    bbase[t] = ex;
    bcur[t] = ex;
  }
  if (t == 255) bbase[NB] = val;  // total
}

// Partition edges into bucket-contiguous regions as packed records:
// rec = src | (dstLocal << 17)   (src < 2^17, dstLocal < 2^9)
__global__ __launch_bounds__(256) void k_part(const int* __restrict__ src,
                                              const int* __restrict__ dst,
                                              int* __restrict__ bcur,
                                              int* __restrict__ part) {
  __shared__ int h[NB];
  __shared__ int cur[NB];
  for (int i = threadIdx.x; i < NB; i += 256) h[i] = 0;
  __syncthreads();
  int base = blockIdx.x * EPB;
  for (int i = threadIdx.x; i < EPB; i += 256) {
    int e = base + i;
    if (e < N_EDGES) atomicAdd(&h[dst[e] >> BSHIFT], 1);
  }
  __syncthreads();
  for (int i = threadIdx.x; i < NB; i += 256) {
    int c = h[i];
    cur[i] = c ? atomicAdd(&bcur[i], c) : 0;
  }
  __syncthreads();
  for (int i = threadIdx.x; i < EPB; i += 256) {
    int e = base + i;
    if (e < N_EDGES) {
      int d = dst[e];
      int b = d >> BSHIFT;
      int pos = atomicAdd(&cur[b], 1);
      part[pos] = src[e] | ((d & 511) << 17);
    }
  }
}

// One block per bucket: count per-node degrees in LDS, scan, emit
// indeg/offs/dis1 (coalesced) and csr_src (scatter within L2-resident region).
__global__ __launch_bounds__(256) void k_build(
    const int* __restrict__ part, const int* __restrict__ bbase,
    int* __restrict__ indeg, int* __restrict__ offs, float* __restrict__ dis1,
    int* __restrict__ csr_src) {
  __shared__ int cnt[512];
  __shared__ int slds[256];
  int b = blockIdx.x;
  int t = threadIdx.x;
  int beg = bbase[b], end = bbase[b + 1];
  for (int i = t; i < 512; i += 256) cnt[i] = 0;
  __syncthreads();
  for (int i = beg + t; i < end; i += 256)
    atomicAdd(&cnt[(part[i] >> 17) & 511], 1);
  __syncthreads();
  int a0 = cnt[2 * t], a1 = cnt[2 * t + 1];
  int pairsum = a0 + a1;
  slds[t] = pairsum;
  __syncthreads();
  int val = pairsum;
  for (int o = 1; o < 256; o <<= 1) {
    int y = (t >= o) ? slds[t - o] : 0;
    __syncthreads();
    val += y;
    slds[t] = val;
    __syncthreads();
  }
  int ex = val - pairsum;  // exclusive over this thread's pair
  int off0 = ex, off1 = ex + a0;
  cnt[2 * t] = off0;  // reuse as scatter cursors
  cnt[2 * t + 1] = off1;
  int node0 = (b << BSHIFT) + 2 * t;
  if (node0 < N_NODES) {
    indeg[node0] = a0;
    offs[node0] = beg + off0;
    dis1[node0] = rsqrtf((float)a0 + 1.f);
  }
  if (node0 + 1 < N_NODES) {
    indeg[node0 + 1] = a1;
    offs[node0 + 1] = beg + off1;
    dis1[node0 + 1] = rsqrtf((float)a1 + 1.f);
  }
  __syncthreads();
  for (int i = beg + t; i < end; i += 256) {
    int p = part[i];
    int loc = (p >> 17) & 511;
    int pos = atomicAdd(&cnt[loc], 1);
    csr_src[beg + pos] = p & 131071;
  }
}

// Tiled fp32 GEMM: Y[r][64] = (X[r][K] @ W[K][64]) * scale[r].
template <int K>
__global__ __launch_bounds__(256) void k_gemm(const float* __restrict__ X,
                                              const float* __restrict__ W,
                                              const float* __restrict__ scale,
                                              float* __restrict__ Y, int nrows) {
  constexpr int C4 = K / 4;  // 16B chunks per row
  __shared__ __align__(16) float Xs[64][K];
  __shared__ __align__(16) float Ws[K][64];
  int t = threadIdx.x;
  int rbase = blockIdx.x * 64;
  for (int idx = t; idx < 64 * C4; idx += 256) {
    int row = idx / C4;
    int c4 = idx % C4;
    int gr = rbase + row;
    if (gr >= nrows) gr = nrows - 1;
    float4 v = *(const float4*)(X + (size_t)gr * K + c4 * 4);
    int c4s = c4 ^ (row & 7);
    *(float4*)&Xs[row][c4s * 4] = v;
  }
  for (int idx = t; idx < K * 16; idx += 256) {
    ((float4*)&Ws[0][0])[idx] = ((const float4*)W)[idx];
  }
  __syncthreads();

  int tx = t & 15, ty = t >> 4;
  int r0 = ty * 4, c0 = tx * 4;
  float acc[4][4] = {};
#pragma unroll 8
  for (int k = 0; k < K; k += 4) {
    float xv[4][4], wv[4][4];
#pragma unroll
    for (int i = 0; i < 4; ++i) {
      int r = r0 + i;
      int c4s = ((k >> 2) ^ (r & 7)) << 2;
      *(float4*)xv[i] = *(const float4*)&Xs[r][c4s];
    }
#pragma unroll
    for (int j = 0; j < 4; ++j)
      *(float4*)wv[j] = *(const float4*)&Ws[k + j][c0];
#pragma unroll
    for (int i = 0; i < 4; ++i)
#pragma unroll
      for (int kk = 0; kk < 4; ++kk)
#pragma unroll
        for (int j = 0; j < 4; ++j)
          acc[i][j] = fmaf(xv[i][kk], wv[kk][j], acc[i][j]);
  }
#pragma unroll
  for (int i = 0; i < 4; ++i) {
    int gr = rbase + r0 + i;
    if (gr < nrows) {
      float sc = scale[gr];
      float4 o;
      o.x = acc[i][0] * sc;
      o.y = acc[i][1] * sc;
      o.z = acc[i][2] * sc;
      o.w = acc[i][3] * sc;
      *(float4*)(Y + (size_t)gr * 64 + c0) = o;
    }
  }
}

// Layer-0 aggregation over prescaled rows h1p (= h1 * dis1), fused with +b1,
// LayerNorm, ReLU, score s[v], block min/max partials.
__global__ __launch_bounds__(256) void k_agg1(
    const float* __restrict__ h1p, const int* __restrict__ offs,
    const int* __restrict__ indeg, const int* __restrict__ csr_src,
    const float* __restrict__ dis1, const float* __restrict__ b1,
    const float* __restrict__ gamma, const float* __restrict__ beta,
    float* __restrict__ h, float* __restrict__ s, float* __restrict__ mmpart) {
  int lane = threadIdx.x & 63;
  int wid = blockIdx.x * 4 + (threadIdx.x >> 6);
  int nw = gridDim.x * 4;
  float bmin = __builtin_inff(), bmax = -__builtin_inff();
  for (int v = wid; v < N_NODES; v += nw) {
    int beg = offs[v];
    int deg = indeg[v];
    float disv = dis1[v];
    float acc = h1p[v * 64 + lane];  // self-loop term (prescaled)
    for (int c = 0; c < deg; c += 64) {
      int m = deg - c;
      if (m > 64) m = 64;
      int ul = (lane < m) ? csr_src[beg + c + lane] : 0;
      int j = 0;
      for (; j + 8 <= m; j += 8) {
        int u0 = __shfl(ul, j + 0), u1 = __shfl(ul, j + 1);
        int u2 = __shfl(ul, j + 2), u3 = __shfl(ul, j + 3);
        int u4 = __shfl(ul, j + 4), u5 = __shfl(ul, j + 5);
        int u6 = __shfl(ul, j + 6), u7 = __shfl(ul, j + 7);
        float a0 = h1p[u0 * 64 + lane], a1 = h1p[u1 * 64 + lane];
        float a2 = h1p[u2 * 64 + lane], a3 = h1p[u3 * 64 + lane];
        float a4 = h1p[u4 * 64 + lane], a5 = h1p[u5 * 64 + lane];
        float a6 = h1p[u6 * 64 + lane], a7 = h1p[u7 * 64 + lane];
        acc += ((a0 + a1) + (a2 + a3)) + ((a4 + a5) + (a6 + a7));
      }
      for (; j < m; ++j) {
        int u = __shfl(ul, j);
        acc += h1p[u * 64 + lane];
      }
    }
    acc = disv * acc + b1[lane];
    float mu = wave_sum(acc) * (1.f / 64.f);
    float d = acc - mu;
    float var = wave_sum(d * d) * (1.f / 64.f);
    float hn = d * rsqrtf(var + LN_EPS) * gamma[lane] + beta[lane];
    hn = fmaxf(hn, 0.f);
    h[v * 64 + lane] = hn;
    float sv = sqrtf(wave_sum(hn * hn));  // wave-uniform
    if (lane == 0) s[v] = sv;
    bmin = fminf(bmin, sv);
    bmax = fmaxf(bmax, sv);
  }
  __shared__ float lmin[4], lmax[4];
  if ((threadIdx.x & 63) == 0) {
    lmin[threadIdx.x >> 6] = bmin;
    lmax[threadIdx.x >> 6] = bmax;
  }
  __syncthreads();
  if (threadIdx.x == 0) {
    mmpart[blockIdx.x * 2] = fminf(fminf(lmin[0], lmin[1]), fminf(lmin[2], lmin[3]));
    mmpart[blockIdx.x * 2 + 1] = fmaxf(fmaxf(lmax[0], lmax[1]), fmaxf(lmax[2], lmax[3]));
  }
}

__global__ void k_minmax2(const float* __restrict__ mmpart, float* __restrict__ smm,
                          int nblk) {
  int t = threadIdx.x;  // 256
  float mn = __builtin_inff(), mx = -__builtin_inff();
  for (int i = t; i < nblk; i += 256) {
    mn = fminf(mn, mmpart[i * 2]);
    mx = fmaxf(mx, mmpart[i * 2 + 1]);
  }
  for (int o = 32; o; o >>= 1) {
    mn = fminf(mn, __shfl_xor(mn, o, 64));
    mx = fmaxf(mx, __shfl_xor(mx, o, 64));
  }
  __shared__ float a[4], b[4];
  if ((t & 63) == 0) { a[t >> 6] = mn; b[t >> 6] = mx; }
  __syncthreads();
  if (t == 0) {
    smm[0] = fminf(fminf(a[0], a[1]), fminf(a[2], a[3]));
    smm[1] = fmaxf(fmaxf(b[0], b[1]), fmaxf(b[2], b[3]));
  }
}

__global__ void k_dis2(const float* __restrict__ s, const float* __restrict__ smm,
                       const int* __restrict__ indeg, float* __restrict__ dis2) {
  int v = blockIdx.x * blockDim.x + threadIdx.x;
  if (v < N_NODES) {
    float inv = 1.f / (smm[1] - smm[0] + 1e-8f);
    float sn = (s[v] - smm[0]) * inv;
    float d = (sn > THRV) ? (float)indeg[v] : 0.f;
    dis2[v] = rsqrtf(d + 1.f);
  }
}

// Layer-1 masked aggregation over prescaled rows h2p (= h2 * dis2), fused with
// +b2 and log_softmax into d_out.
__global__ __launch_bounds__(256) void k_agg2(
    const float* __restrict__ h2p, const int* __restrict__ offs,
    const int* __restrict__ indeg, const int* __restrict__ csr_src,
    const float* __restrict__ s, const float* __restrict__ smm,
    const float* __restrict__ dis2, const float* __restrict__ b2,
    float* __restrict__ out) {
  int lane = threadIdx.x & 63;
  int wid = blockIdx.x * 4 + (threadIdx.x >> 6);
  int nw = gridDim.x * 4;
  float smin = smm[0];
  float inv = 1.f / (smm[1] - smm[0] + 1e-8f);
  for (int v = wid; v < N_NODES; v += nw) {
    float disv = dis2[v];
    float sn = (s[v] - smin) * inv;
    float acc = h2p[v * 64 + lane];  // self-loop term (prescaled)
    if (sn > THRV) {
      int beg = offs[v];
      int deg = indeg[v];
      for (int c = 0; c < deg; c += 64) {
        int m = deg - c;
        if (m > 64) m = 64;
        int ul = (lane < m) ? csr_src[beg + c + lane] : 0;
        int j = 0;
        for (; j + 8 <= m; j += 8) {
          int u0 = __shfl(ul, j + 0), u1 = __shfl(ul, j + 1);
          int u2 = __shfl(ul, j + 2), u3 = __shfl(ul, j + 3);
          int u4 = __shfl(ul, j + 4), u5 = __shfl(ul, j + 5);
          int u6 = __shfl(ul, j + 6), u7 = __shfl(ul, j + 7);
          float a0 = h2p[u0 * 64 + lane], a1 = h2p[u1 * 64 + lane];
          float a2 = h2p[u2 * 64 + lane], a3 = h2p[u3 * 64 + lane];
          float a4 = h2p[u4 * 64 + lane], a5 = h2p[u5 * 64 + lane];
          float a6 = h2p[u6 * 64 + lane], a7 = h2p[u7 * 64 + lane];
          acc += ((a0 + a1) + (a2 + a3)) + ((a4 + a5) + (a6 + a7));
        }
        for (; j < m; ++j) {
          int u = __shfl(ul, j);
          acc += h2p[u * 64 + lane];
        }
      }
    }
    acc = disv * acc + b2[lane];
    float m = wave_max(acc);
    float p = expf(acc - m);
    float sum = wave_sum(p);
    out[v * 64 + lane] = acc - m - logf(sum);
  }
}

extern "C" void kernel_launch(void* const* d_in, const int* in_sizes, int n_in,
                              void* d_out, int out_size, void* d_ws, size_t ws_size,
                              hipStream_t stream) {
  const float* x = (const float*)d_in[0];
  const float* W1 = (const float*)d_in[1];
  const float* b1 = (const float*)d_in[2];
  const float* W2 = (const float*)d_in[3];
  const float* b2 = (const float*)d_in[4];
  const float* gamma = (const float*)d_in[5];
  const float* beta = (const float*)d_in[6];
  const int* ei = (const int*)d_in[7];
  const int* src = ei;
  const int* dst = ei + N_EDGES;
  float* out = (float*)d_out;

  char* ws = (char*)d_ws;
  size_t off = 0;
  auto alloc = [&](size_t bytes) {
    void* p = ws + off;
    off += (bytes + 255) & ~(size_t)255;
    return p;
  };
  int* indeg = (int*)alloc(N_NODES * 4);
  int* offs = (int*)alloc(N_NODES * 4);
  int* bcnt = (int*)alloc(NB * 4);
  int* bbase = (int*)alloc((NB + 1) * 4);
  int* bcur = (int*)alloc(NB * 4);
  int* csr_src = (int*)alloc(N_EDGES * 4);
  float* s = (float*)alloc(N_NODES * 4);
  float* dis1 = (float*)alloc(N_NODES * 4);
  float* dis2 = (float*)alloc(N_NODES * 4);
  float* mmpart = (float*)alloc(GRID_AGG * 2 * 4);
  float* smm = (float*)alloc(256);
  float* h1 = (float*)alloc((size_t)N_NODES * 64 * 4);
  float* h = (float*)alloc((size_t)N_NODES * 64 * 4);
  int* part = (int*)h1;  // alias: part is dead before gemm1 writes h1
  (void)ws_size;
  (void)n_in;
  (void)in_sizes;
  (void)out_size;

  hipMemsetAsync(bcnt, 0, NB * 4, stream);
  k_bcount<<<NPB, 256, 0, stream>>>(dst, bcnt);
  k_bscan<<<1, 256, 0, stream>>>(bcnt, bbase, bcur);
  k_part<<<NPB, 256, 0, stream>>>(src, dst, bcur, part);
  k_build<<<NB, 256, 0, stream>>>(part, bbase, indeg, offs, dis1, csr_src);
  int gemm_grid = (N_NODES + 63) / 64;  // 1563
  k_gemm<IN_F><<<gemm_grid, 256, 0, stream>>>(x, W1, dis1, h1, N_NODES);
  k_agg1<<<GRID_AGG, 256, 0, stream>>>(h1, offs, indeg, csr_src, dis1, b1, gamma,
                                       beta, h, s, mmpart);
  k_minmax2<<<1, 256, 0, stream>>>(mmpart, smm, GRID_AGG);
  k_dis2<<<(N_NODES + 255) / 256, 256, 0, stream>>>(s, smm, indeg, dis2);
  k_gemm<H_F><<<gemm_grid, 256, 0, stream>>>(h, W2, dis2, h1 /* reuse as h2p */, N_NODES);
  k_agg2<<<GRID_AGG, 256, 0, stream>>>(h1, offs, indeg, csr_src, s, smm, dis2, b2,
                                       out);
}